// Round 16
// baseline (808.473 us; speedup 1.0000x reference)
//
#include <hip/hip_runtime.h>
#include <hip/hip_bf16.h>
#include <math.h>

using bf16 = __hip_bfloat16;

#define B_  8
#define S_  1024
#define D_  768
#define H_  8
#define DH_ 96
#define TD_ 2304   // 3*D
#define L_  3
#define GK_ 1536   // gate concat K
#define NC_ 3072   // fused Y+qkv N
#define MAXE_ 98304  // CSR capacity (strict bound 90112)

typedef __attribute__((ext_vector_type(8))) short short8v;
typedef __attribute__((ext_vector_type(4))) float f32x4;

static inline size_t align_up(size_t x) { return (x + 255) & ~(size_t)255; }

__device__ inline short bfbits(float f) {
    unsigned x = __float_as_uint(f);
    unsigned r = (x + 0x7fffu + ((x >> 16) & 1u)) >> 16;   // RNE
    return (short)r;
}
__device__ inline float bf2f(const bf16 s) { return __bfloat162float(s); }

// ---------------------------------------------------------------------------
// sim = x@x^T, symmetric: 64x64 triangle tiles (bx<=by), 256-thread blocks
// (4 waves/tile -> ~17 waves/CU), 4x4 micro-tile. Each output element is
// computed by ONE thread with the same k-ascending fmaf chain as all prior
// rounds -> bit-identical sim -> same kNN graph. Tile + mirrored transpose
// stores; overlapping writes carry identical bits (benign).
// ---------------------------------------------------------------------------
__global__ __launch_bounds__(256)
void gemm_f32_bt_k(const float* __restrict__ X, long long xbs, int ldx,
                   const float* __restrict__ W, long long wbs, int ldw,
                   float* __restrict__ C, long long cbs, int ldc, int K)
{
    // XCD swizzle: 1088 = 8*136 -> XCD i gets batch i
    int flat = blockIdx.x;
    flat = (flat & 7) * 136 + (flat >> 3);
    const int bz = flat / 136;
    const int t = flat % 136;
    int by = (int)((sqrtf(8.0f * (float)t + 1.0f) - 1.0f) * 0.5f);
    while ((by + 1) * (by + 2) / 2 <= t) ++by;
    while (by * (by + 1) / 2 > t) --by;
    const int bx = t - by * (by + 1) / 2;   // bx <= by

    __shared__ float As[16][68];
    __shared__ float Bs[16][68];
    X += (long long)bz * xbs;
    W += (long long)bz * wbs;
    C += (long long)bz * cbs;
    const int tid = threadIdx.x;
    const int tx = tid & 15, ty = tid >> 4;       // both 0..15
    const int m0 = by * 64, n0 = bx * 64;

    const int sr = tid >> 2, jq = tid & 3;        // staging: row 0..63, chunk 0..3

    auto ldA = [&](int k0) {
        return *(const float4*)&X[(long long)(m0 + sr) * ldx + k0 + jq * 4];
    };
    auto ldB = [&](int k0) {
        return *(const float4*)&W[(long long)(n0 + sr) * ldw + k0 + jq * 4];
    };
    auto stage = [&](float4 a, float4 b) {
        As[jq * 4 + 0][sr] = a.x; As[jq * 4 + 1][sr] = a.y;
        As[jq * 4 + 2][sr] = a.z; As[jq * 4 + 3][sr] = a.w;
        Bs[jq * 4 + 0][sr] = b.x; Bs[jq * 4 + 1][sr] = b.y;
        Bs[jq * 4 + 2][sr] = b.z; Bs[jq * 4 + 3][sr] = b.w;
    };

    float acc[4][4] = {};
    {
        float4 a = ldA(0), b = ldB(0);
        stage(a, b);
    }
    __syncthreads();

    for (int k0 = 0; k0 < K; k0 += 16) {
        const bool more = (k0 + 16) < K;
        float4 na, nb;
        if (more) { na = ldA(k0 + 16); nb = ldB(k0 + 16); }
#pragma unroll
        for (int kk = 0; kk < 16; ++kk) {
            float4 a0 = *(const float4*)&As[kk][ty * 4];
            float4 b0 = *(const float4*)&Bs[kk][tx * 4];
            float a[4] = {a0.x, a0.y, a0.z, a0.w};
            float b[4] = {b0.x, b0.y, b0.z, b0.w};
#pragma unroll
            for (int i = 0; i < 4; ++i)
#pragma unroll
                for (int j = 0; j < 4; ++j)
                    acc[i][j] = fmaf(a[i], b[j], acc[i][j]);
        }
        if (more) {
            __syncthreads();
            stage(na, nb);
            __syncthreads();
        }
    }
    // direct tile
#pragma unroll
    for (int i = 0; i < 4; ++i) {
        int row = m0 + ty * 4 + i;
        float4 v = make_float4(acc[i][0], acc[i][1], acc[i][2], acc[i][3]);
        *(float4*)&C[(long long)row * ldc + n0 + tx * 4] = v;
    }
    // mirrored tile (transpose); identical bits where regions overlap
#pragma unroll
    for (int j = 0; j < 4; ++j) {
        int mrow = n0 + tx * 4 + j;
        float4 v = make_float4(acc[0][j], acc[1][j], acc[2][j], acc[3][j]);
        *(float4*)&C[(long long)mrow * ldc + m0 + ty * 4] = v;
    }
}

// ---------------------------------------------------------------------------
// bf16 MFMA GEMM (m97 structure): C[m,n] = sum_k X[m,k]*W[n,k] (+bias)
// MT = M-tile (128 or 64); N-tile fixed 128. 4 waves; wave = (MT/2) x 64.
// OUTMODE 0: f32 C (+bias). 2: bf16 Cb (+bias).
// OUTMODE 3: column-split: n<ncut -> Cb (no bias); n>=ncut -> Cb2 (+bias[n-ncut]).
// ---------------------------------------------------------------------------
template<int OUTMODE, int MT>
__global__ __launch_bounds__(256)
void mfma_gemm_k(const bf16* __restrict__ X, int ldx,
                 const bf16* __restrict__ W, int ldw,
                 float* __restrict__ C, int ldc,
                 bf16* __restrict__ Cb, int ldcb,
                 bf16* __restrict__ Cb2, int ldcb2, int ncut,
                 const float* __restrict__ bias, int K)
{
    constexpr int MFR = MT / 32;          // m-frags per wave
    constexpr int AIT = MT / 64;          // A staging iterations (chunks/256)
    __shared__ short As[MT * 32];
    __shared__ short Bs[128 * 32];
    const int tid = threadIdx.x;
    const int l = tid & 63;
    const int w = tid >> 6;
    const int wm = w >> 1, wn = w & 1;
    const int m0 = blockIdx.y * MT, n0 = blockIdx.x * 128;

    const int frow = l & 15;
    const int koff = (l >> 4) * 8;

    f32x4 acc[MFR][4] = {};

    for (int k0 = 0; k0 < K; k0 += 32) {
        __syncthreads();
#pragma unroll
        for (int it = 0; it < AIT; ++it) {
            int c = it * 256 + tid;
            const bf16* ga = X + (long long)(m0 + (c >> 2)) * ldx + k0 + (c & 3) * 8;
            __builtin_amdgcn_global_load_lds(
                (const __attribute__((address_space(1))) void*)ga,
                (__attribute__((address_space(3))) void*)&As[c * 8], 16, 0, 0);
        }
#pragma unroll
        for (int it = 0; it < 2; ++it) {
            int c = it * 256 + tid;
            const bf16* gb = W + (long long)(n0 + (c >> 2)) * ldw + k0 + (c & 3) * 8;
            __builtin_amdgcn_global_load_lds(
                (const __attribute__((address_space(1))) void*)gb,
                (__attribute__((address_space(3))) void*)&Bs[c * 8], 16, 0, 0);
        }
        __syncthreads();

        short8v a[MFR], b[4];
#pragma unroll
        for (int mi = 0; mi < MFR; ++mi)
            a[mi] = *(const short8v*)&As[(wm * (MT / 2) + mi * 16 + frow) * 32 + koff];
#pragma unroll
        for (int ni = 0; ni < 4; ++ni)
            b[ni] = *(const short8v*)&Bs[(wn * 64 + ni * 16 + frow) * 32 + koff];
        __builtin_amdgcn_s_setprio(1);
#pragma unroll
        for (int mi = 0; mi < MFR; ++mi)
#pragma unroll
            for (int ni = 0; ni < 4; ++ni)
                acc[mi][ni] = __builtin_amdgcn_mfma_f32_16x16x32_bf16(
                    a[mi], b[ni], acc[mi][ni], 0, 0, 0);
        __builtin_amdgcn_s_setprio(0);
    }

    const int rbase = (l >> 4) * 4;
    const int ccol = l & 15;
    const bool second = (OUTMODE == 3) && (n0 >= ncut);
#pragma unroll
    for (int mi = 0; mi < MFR; ++mi) {
#pragma unroll
        for (int ni = 0; ni < 4; ++ni) {
            int col = n0 + wn * 64 + ni * 16 + ccol;
            float bv = 0.0f;
            if (OUTMODE != 3) { if (bias) bv = bias[col]; }
            else if (second)  { bv = bias[col - ncut]; }
#pragma unroll
            for (int j = 0; j < 4; ++j) {
                int row = m0 + wm * (MT / 2) + mi * 16 + rbase + j;
                float v = acc[mi][ni][j] + bv;
                if (OUTMODE == 0) {
                    C[(long long)row * ldc + col] = v;
                } else if (OUTMODE == 2) {
                    Cb[(long long)row * ldcb + col] = __float2bfloat16(v);
                } else {  // 3
                    if (second)
                        Cb2[(long long)row * ldcb2 + (col - ncut)] = __float2bfloat16(v);
                    else
                        Cb[(long long)row * ldcb + col] = __float2bfloat16(v);
                }
            }
        }
    }
}

// ---------------------------------------------------------------------------
__global__ void cvt_bf_k(const float* __restrict__ src, bf16* __restrict__ dst, long long n)
{
    long long stride = (long long)gridDim.x * blockDim.x;
    for (long long i = (long long)blockIdx.x * blockDim.x + threadIdx.x; i * 8 < n; i += stride) {
        float4 v0 = ((const float4*)src)[i * 2];
        float4 v1 = ((const float4*)src)[i * 2 + 1];
        short8v o;
        o[0] = bfbits(v0.x); o[1] = bfbits(v0.y); o[2] = bfbits(v0.z); o[3] = bfbits(v0.w);
        o[4] = bfbits(v1.x); o[5] = bfbits(v1.y); o[6] = bfbits(v1.z); o[7] = bfbits(v1.w);
        *(short8v*)&dst[i * 8] = o;
    }
}

// wcat[l][n][k] = bf16( n<768 ? gcn_w[l][n][k] : attn_in_w[l][n-768][k] )
__global__ void cvt_wcat_k(const float* __restrict__ gw, const float* __restrict__ aiw,
                           bf16* __restrict__ wcat)
{
    const long long nch = (long long)L_ * NC_ * D_ / 8;
    long long stride = (long long)gridDim.x * blockDim.x;
    for (long long i = (long long)blockIdx.x * blockDim.x + threadIdx.x; i < nch; i += stride) {
        long long e8 = i * 8;
        int l = (int)(e8 / ((long long)NC_ * D_));
        long long rem = e8 - (long long)l * NC_ * D_;
        int n = (int)(rem / D_);
        int k = (int)(rem - (long long)n * D_);
        const float* src = (n < D_)
            ? gw  + ((size_t)l * D_  + n)        * D_ + k
            : aiw + ((size_t)l * TD_ + (n - D_)) * D_ + k;
        float4 v0 = *(const float4*)src;
        float4 v1 = *(const float4*)(src + 4);
        short8v o;
        o[0] = bfbits(v0.x); o[1] = bfbits(v0.y); o[2] = bfbits(v0.z); o[3] = bfbits(v0.w);
        o[4] = bfbits(v1.x); o[5] = bfbits(v1.y); o[6] = bfbits(v1.z); o[7] = bfbits(v1.w);
        *(short8v*)&wcat[e8] = o;
    }
}

__global__ void zero32_k(unsigned int* __restrict__ p, long long n32)
{
    for (long long i = (long long)blockIdx.x * blockDim.x + threadIdx.x; i < n32;
         i += (long long)gridDim.x * blockDim.x)
        p[i] = 0u;
}

// ---------------------------------------------------------------------------
// Wave-parallel top-5: one wave per row (strict > == lax.top_k tie set).
// ---------------------------------------------------------------------------
__global__ __launch_bounds__(256)
void topk_k(const float* __restrict__ sim, int* __restrict__ idx)
{
    const int r = blockIdx.x * 4 + (threadIdx.x >> 6);
    const int lane = threadIdx.x & 63;
    const float* row = sim + (long long)r * S_;
    const float NEG = -3.4e38f;
    float v0 = NEG, v1 = NEG, v2 = NEG, v3 = NEG, v4 = NEG;
    int i0 = -1, i1 = -1, i2 = -1, i3 = -1, i4 = -1;
#pragma unroll
    for (int j = 0; j < 16; ++j) {
        int t = lane + j * 64;
        float xv = row[t];
        if (xv > v4) {
            v4 = xv; i4 = t;
            if (v4 > v3) { float tv = v3; v3 = v4; v4 = tv; int ti = i3; i3 = i4; i4 = ti; }
            if (v3 > v2) { float tv = v2; v2 = v3; v3 = tv; int ti = i2; i2 = i3; i3 = ti; }
            if (v2 > v1) { float tv = v1; v1 = v2; v2 = tv; int ti = i1; i1 = i2; i2 = ti; }
            if (v1 > v0) { float tv = v0; v0 = v1; v1 = tv; int ti = i0; i0 = i1; i1 = ti; }
        }
    }
    int o0, o1, o2, o3, o4;
#pragma unroll
    for (int round = 0; round < 5; ++round) {
        float bv = v0; int bi = i0;
        if (v1 > bv || (v1 == bv && i1 < bi)) { bv = v1; bi = i1; }
        if (v2 > bv || (v2 == bv && i2 < bi)) { bv = v2; bi = i2; }
        if (v3 > bv || (v3 == bv && i3 < bi)) { bv = v3; bi = i3; }
        if (v4 > bv || (v4 == bv && i4 < bi)) { bv = v4; bi = i4; }
#pragma unroll
        for (int off = 1; off < 64; off <<= 1) {
            float ov = __shfl_xor(bv, off, 64);
            int oi = __shfl_xor(bi, off, 64);
            if (ov > bv || (ov == bv && oi < bi)) { bv = ov; bi = oi; }
        }
        if (i0 == bi) v0 = NEG;
        else if (i1 == bi) v1 = NEG;
        else if (i2 == bi) v2 = NEG;
        else if (i3 == bi) v3 = NEG;
        else if (i4 == bi) v4 = NEG;
        if (round == 0) o0 = bi;
        else if (round == 1) o1 = bi;
        else if (round == 2) o2 = bi;
        else if (round == 3) o3 = bi;
        else o4 = bi;
    }
    if (lane == 0) {
        idx[r * 5 + 0] = o0; idx[r * 5 + 1] = o1; idx[r * 5 + 2] = o2;
        idx[r * 5 + 3] = o3; idx[r * 5 + 4] = o4;
    }
}

__global__ void adj_k(const int* __restrict__ idx, unsigned char* __restrict__ adj)
{
    int r = blockIdx.x * blockDim.x + threadIdx.x;
    if (r >= B_ * S_) return;
    int b = r >> 10, s = r & (S_ - 1);
    unsigned char* Ab = adj + (long long)b * S_ * S_;
    Ab[(long long)s * S_ + s] = 1;
    for (int j = 0; j < 5; ++j) {
        int t = idx[r * 5 + j];
        Ab[(long long)s * S_ + t] = 1;   // races write identical value: benign
        Ab[(long long)t * S_ + s] = 1;
    }
}

// deg + dinv per row
__global__ void deg_dinv_k(const unsigned char* __restrict__ adj,
                           int* __restrict__ deg, float* __restrict__ dinv)
{
    int r = blockIdx.x * blockDim.x + threadIdx.x;
    if (r >= B_ * S_) return;
    const unsigned int* row = (const unsigned int*)(adj + (long long)r * S_);
    int dsum = 0;
    for (int t = 0; t < S_ / 4; ++t)
        dsum += __popc(row[t]);          // bytes are 0/1
    deg[r] = dsum;
    dinv[r] = rsqrtf((float)dsum);
}

// exclusive scan of deg[8192] -> off[8193]; one block of 1024 threads
__global__ __launch_bounds__(1024)
void scan_k(const int* __restrict__ deg, int* __restrict__ off)
{
    __shared__ int buf[1024];
    const int tid = threadIdx.x;
    int loc[8];
    int s = 0;
#pragma unroll
    for (int i = 0; i < 8; ++i) { loc[i] = deg[tid * 8 + i]; s += loc[i]; }
    buf[tid] = s;
    __syncthreads();
    for (int d = 1; d < 1024; d <<= 1) {
        int v = (tid >= d) ? buf[tid - d] : 0;
        __syncthreads();
        buf[tid] += v;
        __syncthreads();
    }
    int base = buf[tid] - s;   // exclusive
#pragma unroll
    for (int i = 0; i < 8; ++i) { off[tid * 8 + i] = base; base += loc[i]; }
    if (tid == 1023) off[B_ * S_] = buf[1023];
}

// CSR fill: one wave per row, ordered compaction (ascending t).
__global__ __launch_bounds__(256)
void csr_fill_k(const unsigned char* __restrict__ adj, const float* __restrict__ dinv,
                const int* __restrict__ off, int* __restrict__ nidx,
                float* __restrict__ nwt)
{
    const int r = blockIdx.x * 4 + (threadIdx.x >> 6);
    const int lane = threadIdx.x & 63;
    const int b = r >> 10;
    const unsigned int* row = (const unsigned int*)(adj + (long long)r * S_);
    unsigned int w0 = row[lane * 4 + 0], w1 = row[lane * 4 + 1];
    unsigned int w2 = row[lane * 4 + 2], w3 = row[lane * 4 + 3];
    int cnt = __popc(w0) + __popc(w1) + __popc(w2) + __popc(w3);
    int pre = cnt;
#pragma unroll
    for (int d = 1; d < 64; d <<= 1) {
        int v = __shfl_up(pre, d, 64);
        if (lane >= d) pre += v;
    }
    int p = off[r] + pre - cnt;
    const float dr = dinv[r];
#pragma unroll
    for (int q = 0; q < 16; ++q) {
        unsigned int word = (q < 4) ? w0 : (q < 8) ? w1 : (q < 12) ? w2 : w3;
        if ((word >> (8 * (q & 3))) & 0xffu) {
            int t = lane * 16 + q;
            nidx[p] = t;
            nwt[p] = dr * dinv[(b << 10) + t];
            ++p;
        }
    }
}

// ---------------------------------------------------------------------------
// Sparse GCN aggregation from CSR; writes bf16 into cat[:, 0:768].
// XCD-swizzled: each XCD handles one batch (Y panel L2-resident).
// ---------------------------------------------------------------------------
__global__ __launch_bounds__(256)
void gcn_agg_k(const int* __restrict__ off, const int* __restrict__ nidx,
               const float* __restrict__ nwt, const bf16* __restrict__ Y,
               const float* __restrict__ gb, bf16* __restrict__ cat)
{
    const int bid = blockIdx.x;
    const int r = (bid & 7) * 1024 + (bid >> 3);   // 8192 % 8 == 0: bijective
    const int tid = threadIdx.x;
    const long long rowbase = (long long)(r & ~(S_ - 1)) * D_;
    const int s = off[r], e = off[r + 1];
    float a0 = 0.f, a1 = 0.f, a2 = 0.f;
#pragma unroll 2
    for (int p = s; p < e; ++p) {
        int t = nidx[p];
        float wt = nwt[p];
        const bf16* yr = Y + rowbase + (long long)t * D_;
        a0 = fmaf(wt, bf2f(yr[tid]), a0);
        a1 = fmaf(wt, bf2f(yr[tid + 256]), a1);
        a2 = fmaf(wt, bf2f(yr[tid + 512]), a2);
    }
    long long cbase = (long long)r * GK_;
    cat[cbase + tid]       = __float2bfloat16(a0 + gb[tid]);
    cat[cbase + tid + 256] = __float2bfloat16(a1 + gb[tid + 256]);
    cat[cbase + tid + 512] = __float2bfloat16(a2 + gb[tid + 512]);
}

// ---------------------------------------------------------------------------
// MFMA flash attention. Block = 128 Q-rows (4 waves x 32), KV tile = 64.
// No-max softmax; T14 async-stage: next tile's K/V loaded to registers
// during compute, written to LDS after the post-compute barrier.
// ---------------------------------------------------------------------------
__global__ __launch_bounds__(256)
void flash_k(const bf16* __restrict__ qkv, bf16* __restrict__ ao)
{
    const int q0 = blockIdx.x * 128;
    const int bh = blockIdx.y;
    const int b = bh >> 3, h = bh & 7;
    const int tid = threadIdx.x;
    const int w = tid >> 6;
    const int l = tid & 63;
    const float scale = 0.10206207261596575f;  // 1/sqrt(96)

    __shared__ short Ks[64][104];
    __shared__ short Vt[96][72];
    __shared__ short Ps[4][32][72];

    const int frow = l & 15;
    const int koff = (l >> 4) * 8;

    // per-thread staging chunk coords (3 chunks each for K and V)
    int krow[3], kc8[3], vrow[3], vc8[3];
#pragma unroll
    for (int ii = 0; ii < 3; ++ii) {
        int c = tid + ii * 256;
        krow[ii] = c / 12; kc8[ii] = c % 12;
        vrow[ii] = c & 63; vc8[ii] = c >> 6;
    }

    short8v qfA[3], qfB[3];
    {
        const bf16* qa = qkv + ((long long)b * S_ + q0 + w * 32 + frow) * TD_ + h * DH_ + koff;
        const bf16* qb = qa + 16 * TD_;
#pragma unroll
        for (int kc = 0; kc < 3; ++kc) {
            qfA[kc] = *(const short8v*)(qa + kc * 32);
            qfB[kc] = *(const short8v*)(qb + kc * 32);
        }
    }

    auto loadKV = [&](int t0, short8v (&kr)[3], short8v (&vr)[3]) {
        const bf16* kb = qkv + ((long long)b * S_ + t0) * TD_ + D_ + h * DH_;
        const bf16* vb = kb + D_;
#pragma unroll
        for (int ii = 0; ii < 3; ++ii) {
            kr[ii] = *(const short8v*)(kb + (long long)krow[ii] * TD_ + kc8[ii] * 8);
            vr[ii] = *(const short8v*)(vb + (long long)vrow[ii] * TD_ + vc8[ii] * 8);
        }
    };
    auto writeKV = [&](const short8v (&kr)[3], const short8v (&vr)[3]) {
#pragma unroll
        for (int ii = 0; ii < 3; ++ii) {
            *(short8v*)&Ks[krow[ii]][kc8[ii] * 8] = kr[ii];
#pragma unroll
            for (int j = 0; j < 8; ++j)
                Vt[vc8[ii] * 8 + j][vrow[ii]] = vr[ii][j];
        }
    };

    float psA[4] = {0.f, 0.f, 0.f, 0.f}, psB[4] = {0.f, 0.f, 0.f, 0.f};
    f32x4 OA[6] = {}, OB[6] = {};

    // prologue: stage tile 0
    {
        short8v kr[3], vr[3];
        loadKV(0, kr, vr);
        writeKV(kr, vr);
    }
    __syncthreads();

    for (int t0 = 0; t0 < S_; t0 += 64) {
        const bool more = (t0 + 64) < S_;
        short8v nkr[3], nvr[3];
        if (more) loadKV(t0 + 64, nkr, nvr);

        // QK^T: 2 m-frags x 4 n-frags
        {
            f32x4 s[2][4] = {};
            __builtin_amdgcn_s_setprio(1);
#pragma unroll
            for (int kc = 0; kc < 3; ++kc) {
#pragma unroll
                for (int ni = 0; ni < 4; ++ni) {
                    short8v kf = *(const short8v*)&Ks[ni * 16 + frow][kc * 32 + koff];
                    s[0][ni] = __builtin_amdgcn_mfma_f32_16x16x32_bf16(qfA[kc], kf, s[0][ni], 0, 0, 0);
                    s[1][ni] = __builtin_amdgcn_mfma_f32_16x16x32_bf16(qfB[kc], kf, s[1][ni], 0, 0, 0);
                }
            }
            __builtin_amdgcn_s_setprio(0);
            int crow = (l >> 4) * 4;
            int ccol = l & 15;
#pragma unroll
            for (int ni = 0; ni < 4; ++ni) {
#pragma unroll
                for (int j = 0; j < 4; ++j) {
                    float pA = __expf(s[0][ni][j] * scale);
                    float pB = __expf(s[1][ni][j] * scale);
                    Ps[w][crow + j][ni * 16 + ccol]      = bfbits(pA);
                    Ps[w][16 + crow + j][ni * 16 + ccol] = bfbits(pB);
                    psA[j] += pA;
                    psB[j] += pB;
                }
            }
        }

        // PV: K=64 as 2 k-chunks
        {
            short8v paA0 = *(const short8v*)&Ps[w][frow][koff];
            short8v paA1 = *(const short8v*)&Ps[w][frow][32 + koff];
            short8v paB0 = *(const short8v*)&Ps[w][16 + frow][koff];
            short8v paB1 = *(const short8v*)&Ps[w][16 + frow][32 + koff];
            __builtin_amdgcn_s_setprio(1);
#pragma unroll
            for (int dt = 0; dt < 6; ++dt) {
                short8v bf0 = *(const short8v*)&Vt[dt * 16 + frow][koff];
                short8v bf1 = *(const short8v*)&Vt[dt * 16 + frow][32 + koff];
                OA[dt] = __builtin_amdgcn_mfma_f32_16x16x32_bf16(paA0, bf0, OA[dt], 0, 0, 0);
                OA[dt] = __builtin_amdgcn_mfma_f32_16x16x32_bf16(paA1, bf1, OA[dt], 0, 0, 0);
                OB[dt] = __builtin_amdgcn_mfma_f32_16x16x32_bf16(paB0, bf0, OB[dt], 0, 0, 0);
                OB[dt] = __builtin_amdgcn_mfma_f32_16x16x32_bf16(paB1, bf1, OB[dt], 0, 0, 0);
            }
            __builtin_amdgcn_s_setprio(0);
        }

        if (more) {
            __syncthreads();          // all waves done reading Ks/Vt
            writeKV(nkr, nvr);        // regs -> LDS (vmcnt waited by compiler)
            __syncthreads();          // tile t0+64 ready
        }
    }

    float invA[4], invB[4];
#pragma unroll
    for (int j = 0; j < 4; ++j) {
        float sA = psA[j], sB = psB[j];
#pragma unroll
        for (int msk = 1; msk < 16; msk <<= 1) {
            sA += __shfl_xor(sA, msk, 64);
            sB += __shfl_xor(sB, msk, 64);
        }
        invA[j] = 1.0f / sA;
        invB[j] = 1.0f / sB;
    }

#pragma unroll
    for (int dt = 0; dt < 6; ++dt) {
#pragma unroll
        for (int j = 0; j < 4; ++j) {
            int rowA = q0 + w * 32 + (l >> 4) * 4 + j;
            int col = h * DH_ + dt * 16 + (l & 15);
            ao[((long long)b * S_ + rowA) * D_ + col] = __float2bfloat16(OA[dt][j] * invA[j]);
            ao[((long long)b * S_ + rowA + 16) * D_ + col] = __float2bfloat16(OB[dt][j] * invB[j]);
        }
    }
}

// ---------------------------------------------------------------------------
// gate sigmoid + fuse + residual + LayerNorm; all-bf16 I/O, f32 internals.
// ---------------------------------------------------------------------------
__global__ __launch_bounds__(256)
void fuse_ln_k(const bf16* __restrict__ gbuf, const bf16* __restrict__ cat,
               bf16* __restrict__ h_bf,
               const float* __restrict__ lng, const float* __restrict__ lnb)
{
    const int r = blockIdx.x;
    const int tid = threadIdx.x;
    const long long base = (long long)r * D_;
    const long long cbase = (long long)r * GK_;
    __shared__ float rs1[4], rs2[4];

    float tv[3];
    float s1 = 0.f, s2 = 0.f;
#pragma unroll
    for (int q = 0; q < 3; ++q) {
        int j = tid + q * 256;
        float g = 1.0f / (1.0f + expf(-bf2f(gbuf[base + j])));
        float gc = bf2f(cat[cbase + j]);
        float av = bf2f(cat[cbase + D_ + j]);
        float t = g * gc + (1.0f - g) * av + bf2f(h_bf[base + j]);
        tv[q] = t;
        s1 += t;
        s2 += t * t;
    }
#pragma unroll
    for (int off = 32; off; off >>= 1) {
        s1 += __shfl_down(s1, off, 64);
        s2 += __shfl_down(s2, off, 64);
    }
    if ((tid & 63) == 0) { rs1[tid >> 6] = s1; rs2[tid >> 6] = s2; }
    __syncthreads();
    float S1 = rs1[0] + rs1[1] + rs1[2] + rs1[3];
    float S2 = rs2[0] + rs2[1] + rs2[2] + rs2[3];
    float mu = S1 * (1.0f / D_);
    float var = S2 * (1.0f / D_) - mu * mu;
    float rinv = rsqrtf(var + 1e-5f);
#pragma unroll
    for (int q = 0; q < 3; ++q) {
        int j = tid + q * 256;
        float v = (tv[q] - mu) * rinv * lng[j] + lnb[j];
        h_bf[base + j] = __float2bfloat16(v);
    }
}

// ---------------------------------------------------------------------------
extern "C" void kernel_launch(void* const* d_in, const int* in_sizes, int n_in,
                              void* d_out, int out_size, void* d_ws, size_t ws_size,
                              hipStream_t stream)
{
    (void)in_sizes; (void)n_in; (void)out_size;
    const float* x          = (const float*)d_in[0];
    const float* gcn_w      = (const float*)d_in[1];
    const float* gcn_b      = (const float*)d_in[2];
    const float* attn_in_w  = (const float*)d_in[3];
    const float* attn_in_b  = (const float*)d_in[4];
    const float* attn_out_w = (const float*)d_in[5];
    const float* attn_out_b = (const float*)d_in[6];
    const float* ln_g       = (const float*)d_in[7];
    const float* ln_b       = (const float*)d_in[8];
    const float* gate_w     = (const float*)d_in[9];
    const float* gate_b     = (const float*)d_in[10];
    const float* proj_w     = (const float*)d_in[11];
    const float* proj_b     = (const float*)d_in[12];
    float* out = (float*)d_out;

    char* ws = (char*)d_ws;
    size_t off = 0;
    auto alloc = [&](size_t bytes) { void* p = ws + off; off = align_up(off + bytes); return p; };
    const size_t nBSD = (size_t)B_ * S_ * D_;
    bf16*  h_bf  = (bf16*)alloc(nBSD * 2);
    float* sim   = (float*)alloc((size_t)B_ * S_ * S_ * 4);  // reused as gbuf_bf
    bf16*  gbuf  = (bf16*)sim;
    bf16*  Y_bf  = (bf16*)alloc(nBSD * 2);                   // gcn pre-agg, bf16
    bf16*  cat   = (bf16*)alloc((size_t)B_ * S_ * GK_ * 2);  // [gcn_bf | Yatt_bf]
    bf16*  qkv_bf= (bf16*)alloc((size_t)B_ * S_ * TD_ * 2);
    bf16*  ao_bf = (bf16*)alloc(nBSD * 2);
    unsigned char* adj = (unsigned char*)alloc((size_t)B_ * S_ * S_);
    float* dinv  = (float*)alloc((size_t)B_ * S_ * 4);
    int*   deg   = (int*)alloc((size_t)B_ * S_ * 4);
    int*   offs  = (int*)alloc(((size_t)B_ * S_ + 1) * 4);
    int*   nidx  = (int*)alloc((size_t)MAXE_ * 4);
    float* nwt   = (float*)alloc((size_t)MAXE_ * 4);
    int*   tki   = (int*)alloc((size_t)B_ * S_ * 5 * 4);
    bf16* wcat   = (bf16*)alloc((size_t)L_ * NC_ * D_ * 2);  // [gcn_w ; attn_in_w]
    bf16* aow_bf = (bf16*)alloc((size_t)L_ * D_ * D_ * 2);
    bf16* gtw_bf = (bf16*)alloc((size_t)L_ * D_ * 2 * D_ * 2);
    bf16* pw_bf  = (bf16*)alloc((size_t)D_ * D_ * 2);
    if (off > ws_size) return;

    cvt_bf_k<<<1024, 256, 0, stream>>>(x, h_bf, nBSD);
    cvt_wcat_k<<<2048, 256, 0, stream>>>(gcn_w, attn_in_w, wcat);
    cvt_bf_k<<<1024, 256, 0, stream>>>(attn_out_w, aow_bf, (long long)L_ * D_ * D_);
    cvt_bf_k<<<1024, 256, 0, stream>>>(gate_w, gtw_bf, (long long)L_ * D_ * 2 * D_);
    cvt_bf_k<<<256, 256, 0, stream>>>(proj_w, pw_bf, (long long)D_ * D_);

    // sim = x @ x^T (exact f32 for kNN; symmetric -> 64x64 triangle tiles + mirror)
    gemm_f32_bt_k<<<8 * 136, 256, 0, stream>>>(
        x, (long long)S_ * D_, D_, x, (long long)S_ * D_, D_,
        sim, (long long)S_ * S_, S_, D_);
    topk_k<<<B_ * S_ / 4, 256, 0, stream>>>(sim, tki);
    zero32_k<<<2048, 256, 0, stream>>>((unsigned int*)adj, (long long)B_ * S_ * S_ / 4);
    adj_k<<<(B_ * S_ + 255) / 256, 256, 0, stream>>>(tki, adj);
    deg_dinv_k<<<(B_ * S_ + 255) / 256, 256, 0, stream>>>(adj, deg, dinv);
    scan_k<<<1, 1024, 0, stream>>>(deg, offs);
    csr_fill_k<<<B_ * S_ / 4, 256, 0, stream>>>(adj, dinv, offs, nidx, nwt);

    dim3 gD64(D_ / 128, (B_ * S_) / 64);    // 6 x 128  (MT=64 tiles)
    dim3 gNC(NC_ / 128, (B_ * S_) / 128);   // 24 x 64  (MT=128)
    for (int l = 0; l < L_; ++l) {
        const bf16* wc  = wcat + (size_t)l * NC_ * D_;
        const bf16* aow = aow_bf + (size_t)l * D_ * D_;
        const bf16* gtw = gtw_bf + (size_t)l * D_ * 2 * D_;

        // [Y_bf | qkv_bf] = h @ [gcn_w ; attn_in_w]^T  (one fused GEMM)
        mfma_gemm_k<3, 128><<<gNC, 256, 0, stream>>>(
            h_bf, D_, wc, D_, nullptr, 0, Y_bf, D_, qkv_bf, TD_, D_,
            attn_in_b + l * TD_, D_);
        // cat[:, :768] = sparse-agg(CSR, Y_bf) + gcn_b
        gcn_agg_k<<<B_ * S_, 256, 0, stream>>>(offs, nidx, nwt, Y_bf, gcn_b + l * D_, cat);
        // flash attention -> ao_bf
        {
            dim3 g(S_ / 128, B_ * H_);
            flash_k<<<g, 256, 0, stream>>>(qkv_bf, ao_bf);
        }
        // cat[:, 768:] = ao @ attn_out_w^T + attn_out_b (bf16)
        mfma_gemm_k<2, 64><<<gD64, 256, 0, stream>>>(
            ao_bf, D_, aow, D_, nullptr, 0, cat + D_, GK_, nullptr, 0, 0,
            attn_out_b + l * D_, D_);
        // gbuf = cat @ gate_w^T + gate_b   (bf16 logits)
        mfma_gemm_k<2, 64><<<gD64, 256, 0, stream>>>(
            cat, GK_, gtw, GK_, nullptr, 0, gbuf, D_, nullptr, 0, 0,
            gate_b + l * D_, GK_);
        // gate+fuse+residual+LN -> h_bf (in-place residual)
        fuse_ln_k<<<B_ * S_, 256, 0, stream>>>(gbuf, cat, h_bf,
                                               ln_g + l * D_, ln_b + l * D_);
    }

    mfma_gemm_k<0, 64><<<gD64, 256, 0, stream>>>(
        h_bf, D_, pw_bf, D_, out, D_, nullptr, 0, nullptr, 0, 0, proj_b, D_);
}

// Round 17
// 801.671 us; speedup vs baseline: 1.0085x; 1.0085x over previous
//
#include <hip/hip_runtime.h>
#include <hip/hip_bf16.h>
#include <math.h>

using bf16 = __hip_bfloat16;

#define B_  8
#define S_  1024
#define D_  768
#define H_  8
#define DH_ 96
#define TD_ 2304   // 3*D
#define L_  3
#define GK_ 1536   // gate concat K
#define NC_ 3072   // fused Y+qkv N
#define MAXE_ 98304  // CSR capacity (strict bound 90112)

typedef __attribute__((ext_vector_type(8))) short short8v;
typedef __attribute__((ext_vector_type(4))) float f32x4;

static inline size_t align_up(size_t x) { return (x + 255) & ~(size_t)255; }

__device__ inline short bfbits(float f) {
    unsigned x = __float_as_uint(f);
    unsigned r = (x + 0x7fffu + ((x >> 16) & 1u)) >> 16;   // RNE
    return (short)r;
}
__device__ inline float bf2f(const bf16 s) { return __bfloat162float(s); }

// ---------------------------------------------------------------------------
// sim = x@x^T, symmetric: 64x64 triangle tiles (bx<=by), 256 threads, 4x4
// micro-tile, BK=32 (24 barrier pairs vs 48). Each output element is computed
// by ONE thread with the same globally k-ascending fmaf chain as all prior
// rounds -> bit-identical sim -> same kNN graph. Tile + mirrored transpose
// stores; overlapping writes carry identical bits (benign).
// ---------------------------------------------------------------------------
__global__ __launch_bounds__(256)
void gemm_f32_bt_k(const float* __restrict__ X, long long xbs, int ldx,
                   const float* __restrict__ W, long long wbs, int ldw,
                   float* __restrict__ C, long long cbs, int ldc, int K)
{
    // XCD swizzle: 1088 = 8*136 -> XCD i gets batch i
    int flat = blockIdx.x;
    flat = (flat & 7) * 136 + (flat >> 3);
    const int bz = flat / 136;
    const int t = flat % 136;
    int by = (int)((sqrtf(8.0f * (float)t + 1.0f) - 1.0f) * 0.5f);
    while ((by + 1) * (by + 2) / 2 <= t) ++by;
    while (by * (by + 1) / 2 > t) --by;
    const int bx = t - by * (by + 1) / 2;   // bx <= by

    __shared__ float As[32][68];
    __shared__ float Bs[32][68];
    X += (long long)bz * xbs;
    W += (long long)bz * wbs;
    C += (long long)bz * cbs;
    const int tid = threadIdx.x;
    const int tx = tid & 15, ty = tid >> 4;       // both 0..15
    const int m0 = by * 64, n0 = bx * 64;

    const int sr = tid >> 2, jq = tid & 3;        // staging: row 0..63, chunk 0..3

    auto ldA = [&](int k0, int half) {
        return *(const float4*)&X[(long long)(m0 + sr) * ldx + k0 + half * 16 + jq * 4];
    };
    auto ldB = [&](int k0, int half) {
        return *(const float4*)&W[(long long)(n0 + sr) * ldw + k0 + half * 16 + jq * 4];
    };
    auto stage = [&](float4 a0, float4 a1, float4 b0, float4 b1) {
        As[jq * 4 + 0][sr] = a0.x; As[jq * 4 + 1][sr] = a0.y;
        As[jq * 4 + 2][sr] = a0.z; As[jq * 4 + 3][sr] = a0.w;
        As[16 + jq * 4 + 0][sr] = a1.x; As[16 + jq * 4 + 1][sr] = a1.y;
        As[16 + jq * 4 + 2][sr] = a1.z; As[16 + jq * 4 + 3][sr] = a1.w;
        Bs[jq * 4 + 0][sr] = b0.x; Bs[jq * 4 + 1][sr] = b0.y;
        Bs[jq * 4 + 2][sr] = b0.z; Bs[jq * 4 + 3][sr] = b0.w;
        Bs[16 + jq * 4 + 0][sr] = b1.x; Bs[16 + jq * 4 + 1][sr] = b1.y;
        Bs[16 + jq * 4 + 2][sr] = b1.z; Bs[16 + jq * 4 + 3][sr] = b1.w;
    };

    float acc[4][4] = {};
    {
        float4 a0 = ldA(0, 0), a1 = ldA(0, 1);
        float4 b0 = ldB(0, 0), b1 = ldB(0, 1);
        stage(a0, a1, b0, b1);
    }
    __syncthreads();

    for (int k0 = 0; k0 < K; k0 += 32) {
        const bool more = (k0 + 32) < K;
        float4 na0, na1, nb0, nb1;
        if (more) {
            na0 = ldA(k0 + 32, 0); na1 = ldA(k0 + 32, 1);
            nb0 = ldB(k0 + 32, 0); nb1 = ldB(k0 + 32, 1);
        }
#pragma unroll
        for (int kk = 0; kk < 32; ++kk) {
            float4 a0 = *(const float4*)&As[kk][ty * 4];
            float4 b0 = *(const float4*)&Bs[kk][tx * 4];
            float a[4] = {a0.x, a0.y, a0.z, a0.w};
            float b[4] = {b0.x, b0.y, b0.z, b0.w};
#pragma unroll
            for (int i = 0; i < 4; ++i)
#pragma unroll
                for (int j = 0; j < 4; ++j)
                    acc[i][j] = fmaf(a[i], b[j], acc[i][j]);
        }
        if (more) {
            __syncthreads();
            stage(na0, na1, nb0, nb1);
            __syncthreads();
        }
    }
    // direct tile
#pragma unroll
    for (int i = 0; i < 4; ++i) {
        int row = m0 + ty * 4 + i;
        float4 v = make_float4(acc[i][0], acc[i][1], acc[i][2], acc[i][3]);
        *(float4*)&C[(long long)row * ldc + n0 + tx * 4] = v;
    }
    // mirrored tile (transpose); identical bits where regions overlap
#pragma unroll
    for (int j = 0; j < 4; ++j) {
        int mrow = n0 + tx * 4 + j;
        float4 v = make_float4(acc[0][j], acc[1][j], acc[2][j], acc[3][j]);
        *(float4*)&C[(long long)mrow * ldc + m0 + ty * 4] = v;
    }
}

// ---------------------------------------------------------------------------
// bf16 MFMA GEMM (m97 structure): C[m,n] = sum_k X[m,k]*W[n,k] (+bias)
// MT = M-tile (128 or 64); N-tile fixed 128. 4 waves; wave = (MT/2) x 64.
// OUTMODE 0: f32 C (+bias). 2: bf16 Cb (+bias).
// OUTMODE 3: column-split: n<ncut -> Cb (no bias); n>=ncut -> Cb2 (+bias[n-ncut]).
// ---------------------------------------------------------------------------
template<int OUTMODE, int MT>
__global__ __launch_bounds__(256)
void mfma_gemm_k(const bf16* __restrict__ X, int ldx,
                 const bf16* __restrict__ W, int ldw,
                 float* __restrict__ C, int ldc,
                 bf16* __restrict__ Cb, int ldcb,
                 bf16* __restrict__ Cb2, int ldcb2, int ncut,
                 const float* __restrict__ bias, int K)
{
    constexpr int MFR = MT / 32;          // m-frags per wave
    constexpr int AIT = MT / 64;          // A staging iterations (chunks/256)
    __shared__ short As[MT * 32];
    __shared__ short Bs[128 * 32];
    const int tid = threadIdx.x;
    const int l = tid & 63;
    const int w = tid >> 6;
    const int wm = w >> 1, wn = w & 1;
    const int m0 = blockIdx.y * MT, n0 = blockIdx.x * 128;

    const int frow = l & 15;
    const int koff = (l >> 4) * 8;

    f32x4 acc[MFR][4] = {};

    for (int k0 = 0; k0 < K; k0 += 32) {
        __syncthreads();
#pragma unroll
        for (int it = 0; it < AIT; ++it) {
            int c = it * 256 + tid;
            const bf16* ga = X + (long long)(m0 + (c >> 2)) * ldx + k0 + (c & 3) * 8;
            __builtin_amdgcn_global_load_lds(
                (const __attribute__((address_space(1))) void*)ga,
                (__attribute__((address_space(3))) void*)&As[c * 8], 16, 0, 0);
        }
#pragma unroll
        for (int it = 0; it < 2; ++it) {
            int c = it * 256 + tid;
            const bf16* gb = W + (long long)(n0 + (c >> 2)) * ldw + k0 + (c & 3) * 8;
            __builtin_amdgcn_global_load_lds(
                (const __attribute__((address_space(1))) void*)gb,
                (__attribute__((address_space(3))) void*)&Bs[c * 8], 16, 0, 0);
        }
        __syncthreads();

        short8v a[MFR], b[4];
#pragma unroll
        for (int mi = 0; mi < MFR; ++mi)
            a[mi] = *(const short8v*)&As[(wm * (MT / 2) + mi * 16 + frow) * 32 + koff];
#pragma unroll
        for (int ni = 0; ni < 4; ++ni)
            b[ni] = *(const short8v*)&Bs[(wn * 64 + ni * 16 + frow) * 32 + koff];
        __builtin_amdgcn_s_setprio(1);
#pragma unroll
        for (int mi = 0; mi < MFR; ++mi)
#pragma unroll
            for (int ni = 0; ni < 4; ++ni)
                acc[mi][ni] = __builtin_amdgcn_mfma_f32_16x16x32_bf16(
                    a[mi], b[ni], acc[mi][ni], 0, 0, 0);
        __builtin_amdgcn_s_setprio(0);
    }

    const int rbase = (l >> 4) * 4;
    const int ccol = l & 15;
    const bool second = (OUTMODE == 3) && (n0 >= ncut);
#pragma unroll
    for (int mi = 0; mi < MFR; ++mi) {
#pragma unroll
        for (int ni = 0; ni < 4; ++ni) {
            int col = n0 + wn * 64 + ni * 16 + ccol;
            float bv = 0.0f;
            if (OUTMODE != 3) { if (bias) bv = bias[col]; }
            else if (second)  { bv = bias[col - ncut]; }
#pragma unroll
            for (int j = 0; j < 4; ++j) {
                int row = m0 + wm * (MT / 2) + mi * 16 + rbase + j;
                float v = acc[mi][ni][j] + bv;
                if (OUTMODE == 0) {
                    C[(long long)row * ldc + col] = v;
                } else if (OUTMODE == 2) {
                    Cb[(long long)row * ldcb + col] = __float2bfloat16(v);
                } else {  // 3
                    if (second)
                        Cb2[(long long)row * ldcb2 + (col - ncut)] = __float2bfloat16(v);
                    else
                        Cb[(long long)row * ldcb + col] = __float2bfloat16(v);
                }
            }
        }
    }
}

// ---------------------------------------------------------------------------
__global__ void cvt_bf_k(const float* __restrict__ src, bf16* __restrict__ dst, long long n)
{
    long long stride = (long long)gridDim.x * blockDim.x;
    for (long long i = (long long)blockIdx.x * blockDim.x + threadIdx.x; i * 8 < n; i += stride) {
        float4 v0 = ((const float4*)src)[i * 2];
        float4 v1 = ((const float4*)src)[i * 2 + 1];
        short8v o;
        o[0] = bfbits(v0.x); o[1] = bfbits(v0.y); o[2] = bfbits(v0.z); o[3] = bfbits(v0.w);
        o[4] = bfbits(v1.x); o[5] = bfbits(v1.y); o[6] = bfbits(v1.z); o[7] = bfbits(v1.w);
        *(short8v*)&dst[i * 8] = o;
    }
}

// wcat[l][n][k] = bf16( n<768 ? gcn_w[l][n][k] : attn_in_w[l][n-768][k] )
__global__ void cvt_wcat_k(const float* __restrict__ gw, const float* __restrict__ aiw,
                           bf16* __restrict__ wcat)
{
    const long long nch = (long long)L_ * NC_ * D_ / 8;
    long long stride = (long long)gridDim.x * blockDim.x;
    for (long long i = (long long)blockIdx.x * blockDim.x + threadIdx.x; i < nch; i += stride) {
        long long e8 = i * 8;
        int l = (int)(e8 / ((long long)NC_ * D_));
        long long rem = e8 - (long long)l * NC_ * D_;
        int n = (int)(rem / D_);
        int k = (int)(rem - (long long)n * D_);
        const float* src = (n < D_)
            ? gw  + ((size_t)l * D_  + n)        * D_ + k
            : aiw + ((size_t)l * TD_ + (n - D_)) * D_ + k;
        float4 v0 = *(const float4*)src;
        float4 v1 = *(const float4*)(src + 4);
        short8v o;
        o[0] = bfbits(v0.x); o[1] = bfbits(v0.y); o[2] = bfbits(v0.z); o[3] = bfbits(v0.w);
        o[4] = bfbits(v1.x); o[5] = bfbits(v1.y); o[6] = bfbits(v1.z); o[7] = bfbits(v1.w);
        *(short8v*)&wcat[e8] = o;
    }
}

__global__ void zero32_k(unsigned int* __restrict__ p, long long n32)
{
    for (long long i = (long long)blockIdx.x * blockDim.x + threadIdx.x; i < n32;
         i += (long long)gridDim.x * blockDim.x)
        p[i] = 0u;
}

// ---------------------------------------------------------------------------
// Wave-parallel top-5: one wave per row (strict > == lax.top_k tie set).
// ---------------------------------------------------------------------------
__global__ __launch_bounds__(256)
void topk_k(const float* __restrict__ sim, int* __restrict__ idx)
{
    const int r = blockIdx.x * 4 + (threadIdx.x >> 6);
    const int lane = threadIdx.x & 63;
    const float* row = sim + (long long)r * S_;
    const float NEG = -3.4e38f;
    float v0 = NEG, v1 = NEG, v2 = NEG, v3 = NEG, v4 = NEG;
    int i0 = -1, i1 = -1, i2 = -1, i3 = -1, i4 = -1;
#pragma unroll
    for (int j = 0; j < 16; ++j) {
        int t = lane + j * 64;
        float xv = row[t];
        if (xv > v4) {
            v4 = xv; i4 = t;
            if (v4 > v3) { float tv = v3; v3 = v4; v4 = tv; int ti = i3; i3 = i4; i4 = ti; }
            if (v3 > v2) { float tv = v2; v2 = v3; v3 = tv; int ti = i2; i2 = i3; i3 = ti; }
            if (v2 > v1) { float tv = v1; v1 = v2; v2 = tv; int ti = i1; i1 = i2; i2 = ti; }
            if (v1 > v0) { float tv = v0; v0 = v1; v1 = tv; int ti = i0; i0 = i1; i1 = ti; }
        }
    }
    int o0, o1, o2, o3, o4;
#pragma unroll
    for (int round = 0; round < 5; ++round) {
        float bv = v0; int bi = i0;
        if (v1 > bv || (v1 == bv && i1 < bi)) { bv = v1; bi = i1; }
        if (v2 > bv || (v2 == bv && i2 < bi)) { bv = v2; bi = i2; }
        if (v3 > bv || (v3 == bv && i3 < bi)) { bv = v3; bi = i3; }
        if (v4 > bv || (v4 == bv && i4 < bi)) { bv = v4; bi = i4; }
#pragma unroll
        for (int off = 1; off < 64; off <<= 1) {
            float ov = __shfl_xor(bv, off, 64);
            int oi = __shfl_xor(bi, off, 64);
            if (ov > bv || (ov == bv && oi < bi)) { bv = ov; bi = oi; }
        }
        if (i0 == bi) v0 = NEG;
        else if (i1 == bi) v1 = NEG;
        else if (i2 == bi) v2 = NEG;
        else if (i3 == bi) v3 = NEG;
        else if (i4 == bi) v4 = NEG;
        if (round == 0) o0 = bi;
        else if (round == 1) o1 = bi;
        else if (round == 2) o2 = bi;
        else if (round == 3) o3 = bi;
        else o4 = bi;
    }
    if (lane == 0) {
        idx[r * 5 + 0] = o0; idx[r * 5 + 1] = o1; idx[r * 5 + 2] = o2;
        idx[r * 5 + 3] = o3; idx[r * 5 + 4] = o4;
    }
}

__global__ void adj_k(const int* __restrict__ idx, unsigned char* __restrict__ adj)
{
    int r = blockIdx.x * blockDim.x + threadIdx.x;
    if (r >= B_ * S_) return;
    int b = r >> 10, s = r & (S_ - 1);
    unsigned char* Ab = adj + (long long)b * S_ * S_;
    Ab[(long long)s * S_ + s] = 1;
    for (int j = 0; j < 5; ++j) {
        int t = idx[r * 5 + j];
        Ab[(long long)s * S_ + t] = 1;   // races write identical value: benign
        Ab[(long long)t * S_ + s] = 1;
    }
}

// deg + dinv per row
__global__ void deg_dinv_k(const unsigned char* __restrict__ adj,
                           int* __restrict__ deg, float* __restrict__ dinv)
{
    int r = blockIdx.x * blockDim.x + threadIdx.x;
    if (r >= B_ * S_) return;
    const unsigned int* row = (const unsigned int*)(adj + (long long)r * S_);
    int dsum = 0;
    for (int t = 0; t < S_ / 4; ++t)
        dsum += __popc(row[t]);          // bytes are 0/1
    deg[r] = dsum;
    dinv[r] = rsqrtf((float)dsum);
}

// exclusive scan of deg[8192] -> off[8193]; one block of 1024 threads
__global__ __launch_bounds__(1024)
void scan_k(const int* __restrict__ deg, int* __restrict__ off)
{
    __shared__ int buf[1024];
    const int tid = threadIdx.x;
    int loc[8];
    int s = 0;
#pragma unroll
    for (int i = 0; i < 8; ++i) { loc[i] = deg[tid * 8 + i]; s += loc[i]; }
    buf[tid] = s;
    __syncthreads();
    for (int d = 1; d < 1024; d <<= 1) {
        int v = (tid >= d) ? buf[tid - d] : 0;
        __syncthreads();
        buf[tid] += v;
        __syncthreads();
    }
    int base = buf[tid] - s;   // exclusive
#pragma unroll
    for (int i = 0; i < 8; ++i) { off[tid * 8 + i] = base; base += loc[i]; }
    if (tid == 1023) off[B_ * S_] = buf[1023];
}

// CSR fill: one wave per row, ordered compaction (ascending t).
__global__ __launch_bounds__(256)
void csr_fill_k(const unsigned char* __restrict__ adj, const float* __restrict__ dinv,
                const int* __restrict__ off, int* __restrict__ nidx,
                float* __restrict__ nwt)
{
    const int r = blockIdx.x * 4 + (threadIdx.x >> 6);
    const int lane = threadIdx.x & 63;
    const int b = r >> 10;
    const unsigned int* row = (const unsigned int*)(adj + (long long)r * S_);
    unsigned int w0 = row[lane * 4 + 0], w1 = row[lane * 4 + 1];
    unsigned int w2 = row[lane * 4 + 2], w3 = row[lane * 4 + 3];
    int cnt = __popc(w0) + __popc(w1) + __popc(w2) + __popc(w3);
    int pre = cnt;
#pragma unroll
    for (int d = 1; d < 64; d <<= 1) {
        int v = __shfl_up(pre, d, 64);
        if (lane >= d) pre += v;
    }
    int p = off[r] + pre - cnt;
    const float dr = dinv[r];
#pragma unroll
    for (int q = 0; q < 16; ++q) {
        unsigned int word = (q < 4) ? w0 : (q < 8) ? w1 : (q < 12) ? w2 : w3;
        if ((word >> (8 * (q & 3))) & 0xffu) {
            int t = lane * 16 + q;
            nidx[p] = t;
            nwt[p] = dr * dinv[(b << 10) + t];
            ++p;
        }
    }
}

// ---------------------------------------------------------------------------
// Sparse GCN aggregation from CSR; writes bf16 into cat[:, 0:768].
// XCD-swizzled: each XCD handles one batch (Y panel L2-resident).
// ---------------------------------------------------------------------------
__global__ __launch_bounds__(256)
void gcn_agg_k(const int* __restrict__ off, const int* __restrict__ nidx,
               const float* __restrict__ nwt, const bf16* __restrict__ Y,
               const float* __restrict__ gb, bf16* __restrict__ cat)
{
    const int bid = blockIdx.x;
    const int r = (bid & 7) * 1024 + (bid >> 3);   // 8192 % 8 == 0: bijective
    const int tid = threadIdx.x;
    const long long rowbase = (long long)(r & ~(S_ - 1)) * D_;
    const int s = off[r], e = off[r + 1];
    float a0 = 0.f, a1 = 0.f, a2 = 0.f;
#pragma unroll 2
    for (int p = s; p < e; ++p) {
        int t = nidx[p];
        float wt = nwt[p];
        const bf16* yr = Y + rowbase + (long long)t * D_;
        a0 = fmaf(wt, bf2f(yr[tid]), a0);
        a1 = fmaf(wt, bf2f(yr[tid + 256]), a1);
        a2 = fmaf(wt, bf2f(yr[tid + 512]), a2);
    }
    long long cbase = (long long)r * GK_;
    cat[cbase + tid]       = __float2bfloat16(a0 + gb[tid]);
    cat[cbase + tid + 256] = __float2bfloat16(a1 + gb[tid + 256]);
    cat[cbase + tid + 512] = __float2bfloat16(a2 + gb[tid + 512]);
}

// ---------------------------------------------------------------------------
// MFMA flash attention. Block = 128 Q-rows (4 waves x 32), KV tile = 64.
// No-max softmax; T14 async-stage: next tile's K/V loaded to registers
// during compute, written to LDS after the post-compute barrier.
// ---------------------------------------------------------------------------
__global__ __launch_bounds__(256)
void flash_k(const bf16* __restrict__ qkv, bf16* __restrict__ ao)
{
    const int q0 = blockIdx.x * 128;
    const int bh = blockIdx.y;
    const int b = bh >> 3, h = bh & 7;
    const int tid = threadIdx.x;
    const int w = tid >> 6;
    const int l = tid & 63;
    const float scale = 0.10206207261596575f;  // 1/sqrt(96)

    __shared__ short Ks[64][104];
    __shared__ short Vt[96][72];
    __shared__ short Ps[4][32][72];

    const int frow = l & 15;
    const int koff = (l >> 4) * 8;

    // per-thread staging chunk coords (3 chunks each for K and V)
    int krow[3], kc8[3], vrow[3], vc8[3];
#pragma unroll
    for (int ii = 0; ii < 3; ++ii) {
        int c = tid + ii * 256;
        krow[ii] = c / 12; kc8[ii] = c % 12;
        vrow[ii] = c & 63; vc8[ii] = c >> 6;
    }

    short8v qfA[3], qfB[3];
    {
        const bf16* qa = qkv + ((long long)b * S_ + q0 + w * 32 + frow) * TD_ + h * DH_ + koff;
        const bf16* qb = qa + 16 * TD_;
#pragma unroll
        for (int kc = 0; kc < 3; ++kc) {
            qfA[kc] = *(const short8v*)(qa + kc * 32);
            qfB[kc] = *(const short8v*)(qb + kc * 32);
        }
    }

    auto loadKV = [&](int t0, short8v (&kr)[3], short8v (&vr)[3]) {
        const bf16* kb = qkv + ((long long)b * S_ + t0) * TD_ + D_ + h * DH_;
        const bf16* vb = kb + D_;
#pragma unroll
        for (int ii = 0; ii < 3; ++ii) {
            kr[ii] = *(const short8v*)(kb + (long long)krow[ii] * TD_ + kc8[ii] * 8);
            vr[ii] = *(const short8v*)(vb + (long long)vrow[ii] * TD_ + vc8[ii] * 8);
        }
    };
    auto writeKV = [&](const short8v (&kr)[3], const short8v (&vr)[3]) {
#pragma unroll
        for (int ii = 0; ii < 3; ++ii) {
            *(short8v*)&Ks[krow[ii]][kc8[ii] * 8] = kr[ii];
#pragma unroll
            for (int j = 0; j < 8; ++j)
                Vt[vc8[ii] * 8 + j][vrow[ii]] = vr[ii][j];
        }
    };

    float psA[4] = {0.f, 0.f, 0.f, 0.f}, psB[4] = {0.f, 0.f, 0.f, 0.f};
    f32x4 OA[6] = {}, OB[6] = {};

    // prologue: stage tile 0
    {
        short8v kr[3], vr[3];
        loadKV(0, kr, vr);
        writeKV(kr, vr);
    }
    __syncthreads();

    for (int t0 = 0; t0 < S_; t0 += 64) {
        const bool more = (t0 + 64) < S_;
        short8v nkr[3], nvr[3];
        if (more) loadKV(t0 + 64, nkr, nvr);

        // QK^T: 2 m-frags x 4 n-frags
        {
            f32x4 s[2][4] = {};
            __builtin_amdgcn_s_setprio(1);
#pragma unroll
            for (int kc = 0; kc < 3; ++kc) {
#pragma unroll
                for (int ni = 0; ni < 4; ++ni) {
                    short8v kf = *(const short8v*)&Ks[ni * 16 + frow][kc * 32 + koff];
                    s[0][ni] = __builtin_amdgcn_mfma_f32_16x16x32_bf16(qfA[kc], kf, s[0][ni], 0, 0, 0);
                    s[1][ni] = __builtin_amdgcn_mfma_f32_16x16x32_bf16(qfB[kc], kf, s[1][ni], 0, 0, 0);
                }
            }
            __builtin_amdgcn_s_setprio(0);
            int crow = (l >> 4) * 4;
            int ccol = l & 15;
#pragma unroll
            for (int ni = 0; ni < 4; ++ni) {
#pragma unroll
                for (int j = 0; j < 4; ++j) {
                    float pA = __expf(s[0][ni][j] * scale);
                    float pB = __expf(s[1][ni][j] * scale);
                    Ps[w][crow + j][ni * 16 + ccol]      = bfbits(pA);
                    Ps[w][16 + crow + j][ni * 16 + ccol] = bfbits(pB);
                    psA[j] += pA;
                    psB[j] += pB;
                }
            }
        }

        // PV: K=64 as 2 k-chunks
        {
            short8v paA0 = *(const short8v*)&Ps[w][frow][koff];
            short8v paA1 = *(const short8v*)&Ps[w][frow][32 + koff];
            short8v paB0 = *(const short8v*)&Ps[w][16 + frow][koff];
            short8v paB1 = *(const short8v*)&Ps[w][16 + frow][32 + koff];
            __builtin_amdgcn_s_setprio(1);
#pragma unroll
            for (int dt = 0; dt < 6; ++dt) {
                short8v bf0 = *(const short8v*)&Vt[dt * 16 + frow][koff];
                short8v bf1 = *(const short8v*)&Vt[dt * 16 + frow][32 + koff];
                OA[dt] = __builtin_amdgcn_mfma_f32_16x16x32_bf16(paA0, bf0, OA[dt], 0, 0, 0);
                OA[dt] = __builtin_amdgcn_mfma_f32_16x16x32_bf16(paA1, bf1, OA[dt], 0, 0, 0);
                OB[dt] = __builtin_amdgcn_mfma_f32_16x16x32_bf16(paB0, bf0, OB[dt], 0, 0, 0);
                OB[dt] = __builtin_amdgcn_mfma_f32_16x16x32_bf16(paB1, bf1, OB[dt], 0, 0, 0);
            }
            __builtin_amdgcn_s_setprio(0);
        }

        if (more) {
            __syncthreads();          // all waves done reading Ks/Vt
            writeKV(nkr, nvr);        // regs -> LDS (vmcnt waited by compiler)
            __syncthreads();          // tile t0+64 ready
        }
    }

    float invA[4], invB[4];
#pragma unroll
    for (int j = 0; j < 4; ++j) {
        float sA = psA[j], sB = psB[j];
#pragma unroll
        for (int msk = 1; msk < 16; msk <<= 1) {
            sA += __shfl_xor(sA, msk, 64);
            sB += __shfl_xor(sB, msk, 64);
        }
        invA[j] = 1.0f / sA;
        invB[j] = 1.0f / sB;
    }

#pragma unroll
    for (int dt = 0; dt < 6; ++dt) {
#pragma unroll
        for (int j = 0; j < 4; ++j) {
            int rowA = q0 + w * 32 + (l >> 4) * 4 + j;
            int col = h * DH_ + dt * 16 + (l & 15);
            ao[((long long)b * S_ + rowA) * D_ + col] = __float2bfloat16(OA[dt][j] * invA[j]);
            ao[((long long)b * S_ + rowA + 16) * D_ + col] = __float2bfloat16(OB[dt][j] * invB[j]);
        }
    }
}

// ---------------------------------------------------------------------------
// gate sigmoid + fuse + residual + LayerNorm; all-bf16 I/O, f32 internals.
// ---------------------------------------------------------------------------
__global__ __launch_bounds__(256)
void fuse_ln_k(const bf16* __restrict__ gbuf, const bf16* __restrict__ cat,
               bf16* __restrict__ h_bf,
               const float* __restrict__ lng, const float* __restrict__ lnb)
{
    const int r = blockIdx.x;
    const int tid = threadIdx.x;
    const long long base = (long long)r * D_;
    const long long cbase = (long long)r * GK_;
    __shared__ float rs1[4], rs2[4];

    float tv[3];
    float s1 = 0.f, s2 = 0.f;
#pragma unroll
    for (int q = 0; q < 3; ++q) {
        int j = tid + q * 256;
        float g = 1.0f / (1.0f + expf(-bf2f(gbuf[base + j])));
        float gc = bf2f(cat[cbase + j]);
        float av = bf2f(cat[cbase + D_ + j]);
        float t = g * gc + (1.0f - g) * av + bf2f(h_bf[base + j]);
        tv[q] = t;
        s1 += t;
        s2 += t * t;
    }
#pragma unroll
    for (int off = 32; off; off >>= 1) {
        s1 += __shfl_down(s1, off, 64);
        s2 += __shfl_down(s2, off, 64);
    }
    if ((tid & 63) == 0) { rs1[tid >> 6] = s1; rs2[tid >> 6] = s2; }
    __syncthreads();
    float S1 = rs1[0] + rs1[1] + rs1[2] + rs1[3];
    float S2 = rs2[0] + rs2[1] + rs2[2] + rs2[3];
    float mu = S1 * (1.0f / D_);
    float var = S2 * (1.0f / D_) - mu * mu;
    float rinv = rsqrtf(var + 1e-5f);
#pragma unroll
    for (int q = 0; q < 3; ++q) {
        int j = tid + q * 256;
        float v = (tv[q] - mu) * rinv * lng[j] + lnb[j];
        h_bf[base + j] = __float2bfloat16(v);
    }
}

// ---------------------------------------------------------------------------
extern "C" void kernel_launch(void* const* d_in, const int* in_sizes, int n_in,
                              void* d_out, int out_size, void* d_ws, size_t ws_size,
                              hipStream_t stream)
{
    (void)in_sizes; (void)n_in; (void)out_size;
    const float* x          = (const float*)d_in[0];
    const float* gcn_w      = (const float*)d_in[1];
    const float* gcn_b      = (const float*)d_in[2];
    const float* attn_in_w  = (const float*)d_in[3];
    const float* attn_in_b  = (const float*)d_in[4];
    const float* attn_out_w = (const float*)d_in[5];
    const float* attn_out_b = (const float*)d_in[6];
    const float* ln_g       = (const float*)d_in[7];
    const float* ln_b       = (const float*)d_in[8];
    const float* gate_w     = (const float*)d_in[9];
    const float* gate_b     = (const float*)d_in[10];
    const float* proj_w     = (const float*)d_in[11];
    const float* proj_b     = (const float*)d_in[12];
    float* out = (float*)d_out;

    char* ws = (char*)d_ws;
    size_t off = 0;
    auto alloc = [&](size_t bytes) { void* p = ws + off; off = align_up(off + bytes); return p; };
    const size_t nBSD = (size_t)B_ * S_ * D_;
    bf16*  h_bf  = (bf16*)alloc(nBSD * 2);
    float* sim   = (float*)alloc((size_t)B_ * S_ * S_ * 4);  // reused as gbuf_bf
    bf16*  gbuf  = (bf16*)sim;
    bf16*  Y_bf  = (bf16*)alloc(nBSD * 2);                   // gcn pre-agg, bf16
    bf16*  cat   = (bf16*)alloc((size_t)B_ * S_ * GK_ * 2);  // [gcn_bf | Yatt_bf]
    bf16*  qkv_bf= (bf16*)alloc((size_t)B_ * S_ * TD_ * 2);
    bf16*  ao_bf = (bf16*)alloc(nBSD * 2);
    unsigned char* adj = (unsigned char*)alloc((size_t)B_ * S_ * S_);
    float* dinv  = (float*)alloc((size_t)B_ * S_ * 4);
    int*   deg   = (int*)alloc((size_t)B_ * S_ * 4);
    int*   offs  = (int*)alloc(((size_t)B_ * S_ + 1) * 4);
    int*   nidx  = (int*)alloc((size_t)MAXE_ * 4);
    float* nwt   = (float*)alloc((size_t)MAXE_ * 4);
    int*   tki   = (int*)alloc((size_t)B_ * S_ * 5 * 4);
    bf16* wcat   = (bf16*)alloc((size_t)L_ * NC_ * D_ * 2);  // [gcn_w ; attn_in_w]
    bf16* aow_bf = (bf16*)alloc((size_t)L_ * D_ * D_ * 2);
    bf16* gtw_bf = (bf16*)alloc((size_t)L_ * D_ * 2 * D_ * 2);
    bf16* pw_bf  = (bf16*)alloc((size_t)D_ * D_ * 2);
    if (off > ws_size) return;

    cvt_bf_k<<<1024, 256, 0, stream>>>(x, h_bf, nBSD);
    cvt_wcat_k<<<2048, 256, 0, stream>>>(gcn_w, attn_in_w, wcat);
    cvt_bf_k<<<1024, 256, 0, stream>>>(attn_out_w, aow_bf, (long long)L_ * D_ * D_);
    cvt_bf_k<<<1024, 256, 0, stream>>>(gate_w, gtw_bf, (long long)L_ * D_ * 2 * D_);
    cvt_bf_k<<<256, 256, 0, stream>>>(proj_w, pw_bf, (long long)D_ * D_);

    // sim = x @ x^T (exact f32 for kNN; symmetric -> 64x64 triangle tiles + mirror)
    gemm_f32_bt_k<<<8 * 136, 256, 0, stream>>>(
        x, (long long)S_ * D_, D_, x, (long long)S_ * D_, D_,
        sim, (long long)S_ * S_, S_, D_);
    topk_k<<<B_ * S_ / 4, 256, 0, stream>>>(sim, tki);
    zero32_k<<<2048, 256, 0, stream>>>((unsigned int*)adj, (long long)B_ * S_ * S_ / 4);
    adj_k<<<(B_ * S_ + 255) / 256, 256, 0, stream>>>(tki, adj);
    deg_dinv_k<<<(B_ * S_ + 255) / 256, 256, 0, stream>>>(adj, deg, dinv);
    scan_k<<<1, 1024, 0, stream>>>(deg, offs);
    csr_fill_k<<<B_ * S_ / 4, 256, 0, stream>>>(adj, dinv, offs, nidx, nwt);

    dim3 gD64(D_ / 128, (B_ * S_) / 64);    // 6 x 128  (MT=64 tiles)
    dim3 gNC(NC_ / 128, (B_ * S_) / 128);   // 24 x 64  (MT=128)
    for (int l = 0; l < L_; ++l) {
        const bf16* wc  = wcat + (size_t)l * NC_ * D_;
        const bf16* aow = aow_bf + (size_t)l * D_ * D_;
        const bf16* gtw = gtw_bf + (size_t)l * D_ * 2 * D_;

        // [Y_bf | qkv_bf] = h @ [gcn_w ; attn_in_w]^T  (one fused GEMM)
        mfma_gemm_k<3, 128><<<gNC, 256, 0, stream>>>(
            h_bf, D_, wc, D_, nullptr, 0, Y_bf, D_, qkv_bf, TD_, D_,
            attn_in_b + l * TD_, D_);
        // cat[:, :768] = sparse-agg(CSR, Y_bf) + gcn_b
        gcn_agg_k<<<B_ * S_, 256, 0, stream>>>(offs, nidx, nwt, Y_bf, gcn_b + l * D_, cat);
        // flash attention -> ao_bf
        {
            dim3 g(S_ / 128, B_ * H_);
            flash_k<<<g, 256, 0, stream>>>(qkv_bf, ao_bf);
        }
        // cat[:, 768:] = ao @ attn_out_w^T + attn_out_b (bf16)
        mfma_gemm_k<2, 64><<<gD64, 256, 0, stream>>>(
            ao_bf, D_, aow, D_, nullptr, 0, cat + D_, GK_, nullptr, 0, 0,
            attn_out_b + l * D_, D_);
        // gbuf = cat @ gate_w^T + gate_b   (bf16 logits)
        mfma_gemm_k<2, 64><<<gD64, 256, 0, stream>>>(
            cat, GK_, gtw, GK_, nullptr, 0, gbuf, D_, nullptr, 0, 0,
            gate_b + l * D_, GK_);
        // gate+fuse+residual+LN -> h_bf (in-place residual)
        fuse_ln_k<<<B_ * S_, 256, 0, stream>>>(gbuf, cat, h_bf,
                                               ln_g + l * D_, ln_b + l * D_);
    }

    mfma_gemm_k<0, 64><<<gD64, 256, 0, stream>>>(
        h_bf, D_, pw_bf, D_, out, D_, nullptr, 0, nullptr, 0, 0, proj_b, D_);
}